// Round 13
// baseline (878.421 us; speedup 1.0000x reference)
//
#include <hip/hip_runtime.h>

typedef _Float16 h2 __attribute__((ext_vector_type(2)));

#define HH 480
#define WW 854
#define HWSZ (HH * WW)
#define PAD 192                 // = 3 * max dilation (64)
#define PSTR 1240               // padded row stride
#define PH (HH + 2 * PAD)       // 864
#define PCELLS (PH * PSTR)      // 1,071,360 cells * 8 B per plane
#define TPSTRIDE 240            // floats per step in tp table
#define RS0 (64 * PSTR * 8)     // k0 row step, bytes
#define RS1 (16 * PSTR * 8)     // k1 row step, bytes

#if __has_builtin(__builtin_amdgcn_exp2f)
#define EXP2(x) __builtin_amdgcn_exp2f(x)
#else
#define EXP2(x) exp2f(x)
#endif

__device__ __forceinline__ float fdot2f(h2 a, h2 b, float c)
{
#if __has_builtin(__builtin_amdgcn_fdot2)
    return __builtin_amdgcn_fdot2(a, b, c, false);
#else
    return fmaf((float)a.x, (float)b.x, fmaf((float)a.y, (float)b.y, c));
#endif
}

__device__ __forceinline__ h2 bch2(unsigned u)
{
    union { unsigned u; h2 h; } v; v.u = u; return v.h;
}
__device__ __forceinline__ unsigned h2u(h2 h)
{
    union { h2 h; unsigned u; } v; v.h = h; return v.u;
}
__device__ __forceinline__ unsigned short hbits(_Float16 h)
{
    union { _Float16 h; unsigned short u; } v; v.h = h; return v.u;
}

// ---------------------------------------------------------------------------
// Init both ping-pong planes (rgb f16, pre-scaled; pad = fp16-max sentinel).
// ---------------------------------------------------------------------------
__global__ __launch_bounds__(256) void init_P(
    const float* __restrict__ xrgb, const float* __restrict__ fs,
    uint2* __restrict__ PA, uint2* __restrict__ PB)
{
    int i = blockIdx.x * 256 + threadIdx.x;
    if (i >= PCELLS) return;
    int y = i / PSTR, x = i - y * PSTR;
    int iy = y - PAD, ix = x - PAD;
    uint2 v;
    if (iy >= 0 && iy < HH && ix >= 0 && ix < WW) {
        int p = iy * WW + ix;
        _Float16 rh = (_Float16)(xrgb[p] * (1.0f / fs[2]));
        _Float16 gh = (_Float16)(xrgb[HWSZ + p] * (1.0f / fs[3]));
        _Float16 bh = (_Float16)(xrgb[2 * HWSZ + p] * (1.0f / fs[4]));
        v = make_uint2(h2u(h2{rh, gh}), h2u(h2{bh, (_Float16)0}));
    } else {
        v = make_uint2(0x7BFF7BFFu, 0x00007BFFu);  // sentinel, q=0
    }
    PA[i] = v;
    PB[i] = v;
}

// ---------------------------------------------------------------------------
// Step-0 q merged into plane A.
// ---------------------------------------------------------------------------
__global__ __launch_bounds__(256) void pack0(
    const float* __restrict__ unary, unsigned* __restrict__ PAw)
{
    int i = blockIdx.x * 256 + threadIdx.x;
    if (i >= HWSZ) return;
    float l0 = unary[i], l1 = unary[HWSZ + i];
    float q = 1.0f / (1.0f + __expf(5.0f * (l1 - l0)));
    int y = i / WW, x = i - y * WW;
    int c = (y + PAD) * PSTR + x + PAD;
    unsigned old = PAw[2 * c + 1];
    PAw[2 * c + 1] = (old & 0xFFFFu) | ((unsigned)hbits((_Float16)q) << 16);
}

// ---------------------------------------------------------------------------
// Precompute per-step tap tables + scalars to global (read back via s_load).
// ---------------------------------------------------------------------------
__global__ __launch_bounds__(256) void build_tp(
    const float* __restrict__ fs, const float* __restrict__ uwArr,
    const float* __restrict__ pwArr,
    const float* __restrict__ w0, const float* __restrict__ w1,
    const float* __restrict__ w2,
    const float* __restrict__ c0, const float* __restrict__ c1,
    float* __restrict__ tp)
{
    int s = blockIdx.x;
    int t = threadIdx.x;
    float* d = tp + s * TPSTRIDE;
    const float NH = -0.72134752044448169f;  // -0.5 * log2(e)

    if (t < 49) {                       // kernel 0: 7x7 dil 64
        int dy = t / 7 - 3, dx = t % 7 - 3;
        float py = dy * 64.0f / fs[0], px = dx * 64.0f / fs[1];
        d[(t / 7) * 8 + t % 7] =
            log2f(w0[s * 49 + t]) + NH * (py * py + px * px);
    } else if (t >= 64 && t < 113) {    // kernel 1: 7x7 dil 16
        int u = t - 64;
        int dy = u / 7 - 3, dx = u % 7 - 3;
        float py = dy * 16.0f / fs[5], px = dx * 16.0f / fs[6];
        d[56 + (u / 7) * 8 + u % 7] =
            log2f(w1[s * 49 + u]) + NH * (py * py + px * px);
    } else if (t >= 128 && t < 209) {   // kernel 2: 9x9 dil 1
        int u = t - 128;
        int dy = u / 9 - 4, dx = u % 9 - 4;
        float py = dy / fs[10], px = dx / fs[11];
        d[112 + (u / 9) * 12 + u % 9] =
            log2f(w2[s * 81 + u]) + NH * (py * py + px * px);
    } else if (t == 224) {
        float r1 = fs[2] / fs[7], r2 = fs[2] / fs[12];
        d[220] = NH;
        d[221] = NH * r1 * r1;
        d[222] = NH * r2 * r2;
        d[223] = c0[s * 4 + 0];  d[224] = c0[s * 4 + 1];
        d[225] = c0[s * 4 + 2];  d[226] = c0[s * 4 + 3];
        d[227] = c1[s * 4 + 0];  d[228] = c1[s * 4 + 1];
        d[229] = c1[s * 4 + 2];  d[230] = c1[s * 4 + 3];
        d[231] = pwArr[s * 3 + 0];
        d[232] = pwArr[s * 3 + 1];
        d[233] = pwArr[s * 3 + 2];
        d[234] = uwArr[s] * 5.0f;
    }
}

// ---------------------------------------------------------------------------
// One tap on an 8-B cell (R10-verified arithmetic, 8 issue ops).
// ---------------------------------------------------------------------------
__device__ __forceinline__ void tap8(uint2 aq, h2 rgp, h2 bqp, float nk,
                                     float tpv, float& A, float& B)
{
    h2 drg = bch2(aq.x) - rgp;
    h2 dbq = bch2(aq.y) - bqp;
    float s1 = fdot2f(drg, drg, 0.0f);
    float db = (float)dbq.x;
    float ssq = fmaf(db, db, s1);
    float e = EXP2(fmaf(ssq, nk, tpv));
    A = fmaf(e, (float)bch2(aq.y).y, A);   // q = hi half -> v_fma_mix
    B += e;
}

// Pair tap: one uint4 = two adjacent cells, serves both pixels of the lane.
__device__ __forceinline__ void tapPair(uint4 a, h2 rg0, h2 bq0, h2 rg1, h2 bq1,
                                        float nk, float tpv,
                                        float& Aa, float& Ba, float& Ab, float& Bb)
{
    tap8(make_uint2(a.x, a.y), rg0, bq0, nk, tpv, Aa, Ba);
    tap8(make_uint2(a.z, a.w), rg1, bq1, nk, tpv, Ab, Bb);
}

// Row of 7 paired b128 loads from one base pointer + immediate offsets.
template <int STEPB>
__device__ __forceinline__ void loadRow(uint4 (&b)[7], const char* __restrict__ rb)
{
#pragma unroll
    for (int j = 0; j < 7; ++j)
        b[j] = *(const uint4*)(rb + (j - 3) * STEPB);
}
__device__ __forceinline__ void compRow(const uint4 (&b)[7],
    const float* __restrict__ tprow, h2 rg0, h2 bq0, h2 rg1, h2 bq1, float nk,
    float& Aa, float& Ba, float& Ab, float& Bb)
{
#pragma unroll
    for (int j = 0; j < 7; ++j)
        tapPair(b[j], rg0, bq0, rg1, bq1, nk, tprow[j], Aa, Ba, Ab, Bb);
}

// k2 row from LDS: even dx -> b128 pair read; odd dx -> two b64 reads.
template <int I>
__device__ __forceinline__ void compK2row(const uint4* __restrict__ T2r,
    const uint2* __restrict__ T2r2,
    const float* __restrict__ tp2, h2 rg0, h2 bq0, h2 rg1, h2 bq1, float nk,
    float& Aa, float& Ba, float& Ab, float& Bb)
{
#pragma unroll
    for (int j = 0; j < 9; ++j) {
        float tpv = tp2[I * 12 + j];
        if ((j & 1) == 0) {
            uint4 a = T2r[I * 68 + j / 2];
            tapPair(a, rg0, bq0, rg1, bq1, nk, tpv, Aa, Ba, Ab, Bb);
        } else {
            uint2 c0 = T2r2[I * 136 + j];
            uint2 c1 = T2r2[I * 136 + j + 1];
            tap8(c0, rg0, bq0, nk, tpv, Aa, Ba);
            tap8(c1, rg1, bq1, nk, tpv, Ab, Bb);
        }
    }
}

// ---------------------------------------------------------------------------
// Fused step, PX=2. Block = (64,4) threads covering a 128x4 px tile.
// k0/k1 from global via running row-base pointers + immediate offsets
// (one address pair per stream); k2 window (13 KB) in LDS.
// ---------------------------------------------------------------------------
template <bool LAST>
__global__ __launch_bounds__(256, 3) void crf_step(
    const uint2* __restrict__ srcP, unsigned* __restrict__ dstPw,
    const float* __restrict__ unary, const float* __restrict__ tpAll,
    int step, float* __restrict__ out)
{
    __shared__ uint4 T2[12 * 68];    // 13056 B

    int tx = threadIdx.x, ty = threadIdx.y;
    int tid = ty * 64 + tx;
    int x0 = blockIdx.x * 128, y0 = blockIdx.y * 4;

    // ---- stage T2: rows y0-4 .. y0+7, cols x0-4.. ----
    for (int c = tid; c < 12 * 68; c += 256) {
        int r = c / 68, col = c - r * 68;
        int gy = y0 - 4 + r;
        T2[c] = *(const uint4*)
            (srcP + (gy + PAD) * PSTR + (x0 - 4 + PAD) + 2 * col);
    }

    int px = x0 + 2 * tx;            // even; pair = (px, px+1)
    int y = y0 + ty;
    bool act = (px < WW);
    int p = y * WW + px;
    int pSafe = act ? p : 0;
    int ccell = (y + PAD) * PSTR + px + PAD;
    const uint2* Pc = srcP + ccell;

    const float* tp0 = tpAll + step * TPSTRIDE;
    const float* tp1 = tp0 + 56;
    const float* tp2 = tp0 + 112;
    const float* sc  = tp0 + 220;
    float nk0 = sc[0], nk1 = sc[1], nk2 = sc[2];

    // running row-base pointers (row 0 of each stream)
    const char* rk0 = (const char*)Pc - 3 * RS0;
    const char* rk1 = (const char*)Pc - 3 * RS1;

    // pre-barrier: center pair, unary pairs, first k0/k1 rows in flight
    uint4 cw = *(const uint4*)Pc;
    float2 unc0 = *(const float2*)(unary + pSafe);
    float2 unc1 = *(const float2*)(unary + HWSZ + pSafe);
    uint4 bA[7], bB[7];
    loadRow<512>(bA, rk0);           // k0 row 0
    loadRow<128>(bB, rk1);           // k1 row 0
    __syncthreads();

    h2 rg0 = bch2(cw.x), bq0 = bch2(cw.y);
    h2 rg1 = bch2(cw.z), bq1 = bch2(cw.w);

    const uint4* T2r  = T2 + ty * 68 + tx;
    const uint2* T2r2 = (const uint2*)T2 + ty * 136 + 2 * tx;

    float A0a = 0, B0a = 0, A0b = 0, B0b = 0;
    float A1a = 0, B1a = 0, A1b = 0, B1b = 0;
    float A2a = 0, B2a = 0, A2b = 0, B2b = 0;

#define C0(I) compRow(bA, tp0 + (I) * 8, rg0, bq0, rg1, bq1, nk0, A0a, B0a, A0b, B0b)
#define C1(I) compRow(bB, tp1 + (I) * 8, rg0, bq0, rg1, bq1, nk1, A1a, B1a, A1b, B1b)
#define L0()  rk0 += RS0; loadRow<512>(bA, rk0)
#define L1()  rk1 += RS1; loadRow<128>(bB, rk1)
#define K2(I) compK2row<I>(T2r, T2r2, tp2, rg0, bq0, rg1, bq1, nk2, A2a, B2a, A2b, B2b)

    // compute current row, then immediately refill the buffer; k2 LDS rows
    // interleave as latency cover. Per-kernel accumulation order preserved.
    C0(0);  L0();  K2(0);
    C1(0);  L1();  K2(1);
    C0(1);  L0();  K2(2);
    C1(1);  L1();  K2(3);
    C0(2);  L0();  K2(4);
    C1(2);  L1();  K2(5);
    C0(3);  L0();  K2(6);
    C1(3);  L1();  K2(7);
    C0(4);  L0();  K2(8);
    C1(4);  L1();
    C0(5);  L0();
    C1(5);  L1();
    C0(6);
    C1(6);

#undef C0
#undef C1
#undef L0
#undef L1
#undef K2

    if (!act) return;

    float pw0 = sc[11], pw1 = sc[12], pw2 = sc[13], uw5 = sc[14];

    // px0
    float m01a = B0a - A0a, m11a = B1a - A1a, m21a = B2a - A2a;
    float r00a = sc[3] * A0a + sc[4] * m01a;
    float r01a = sc[5] * A0a + sc[6] * m01a;
    float r10a = sc[7] * A1a + sc[8] * m11a;
    float r11a = sc[9] * A1a + sc[10] * m11a;
    float o0a = uw5 * unc0.x + pw0 * r00a + pw1 * r10a + pw2 * A2a;
    float o1a = uw5 * unc1.x + pw0 * r01a + pw1 * r11a + pw2 * m21a;

    // px1
    float m01b = B0b - A0b, m11b = B1b - A1b, m21b = B2b - A2b;
    float r00b = sc[3] * A0b + sc[4] * m01b;
    float r01b = sc[5] * A0b + sc[6] * m01b;
    float r10b = sc[7] * A1b + sc[8] * m11b;
    float r11b = sc[9] * A1b + sc[10] * m11b;
    float o0b = uw5 * unc0.y + pw0 * r00b + pw1 * r10b + pw2 * A2b;
    float o1b = uw5 * unc1.y + pw0 * r01b + pw1 * r11b + pw2 * m21b;

    if (LAST) {
        *(float2*)(out + p) = make_float2(o0a, o0b);
        *(float2*)(out + HWSZ + p) = make_float2(o1a, o1b);
    } else {
        float qa = 1.0f / (1.0f + __expf(o1a - o0a));
        float qb = 1.0f / (1.0f + __expf(o1b - o0b));
        dstPw[2 * ccell + 1] = (cw.y & 0xFFFFu) |
                               ((unsigned)hbits((_Float16)qa) << 16);
        dstPw[2 * ccell + 3] = (cw.w & 0xFFFFu) |
                               ((unsigned)hbits((_Float16)qb) << 16);
    }
}

// ---------------------------------------------------------------------------
extern "C" void kernel_launch(void* const* d_in, const int* in_sizes, int n_in,
                              void* d_out, int out_size, void* d_ws, size_t ws_size,
                              hipStream_t stream)
{
    const float* unary = (const float*)d_in[0];
    const float* xrgb  = (const float*)d_in[1];
    const float* fs    = (const float*)d_in[2];
    // d_in[3] = potts_w (dead in reference forward)
    const float* uw    = (const float*)d_in[4];
    const float* pw    = (const float*)d_in[5];
    const float* w0    = (const float*)d_in[6];
    const float* w1    = (const float*)d_in[7];
    const float* w2    = (const float*)d_in[8];
    const float* c0    = (const float*)d_in[9];
    const float* c1    = (const float*)d_in[10];
    float* out = (float*)d_out;

    uint2* PA = (uint2*)d_ws;                               // 8.57 MB
    uint2* PB = (uint2*)((char*)d_ws + (size_t)PCELLS * 8); // 8.57 MB
    float* tpAll = (float*)((char*)d_ws + (size_t)PCELLS * 16);

    init_P<<<(PCELLS + 255) / 256, 256, 0, stream>>>(xrgb, fs, PA, PB);
    pack0<<<(HWSZ + 255) / 256, 256, 0, stream>>>(unary, (unsigned*)PA);
    build_tp<<<5, 256, 0, stream>>>(fs, uw, pw, w0, w1, w2, c0, c1, tpAll);

    dim3 gs((WW + 127) / 128, HH / 4), bs(64, 4);
    for (int s = 0; s < 5; ++s) {
        const uint2* src = (s & 1) ? PB : PA;
        unsigned* dst = (unsigned*)((s & 1) ? PA : PB);
        if (s < 4)
            crf_step<false><<<gs, bs, 0, stream>>>(src, dst, unary, tpAll,
                                                   s, out);
        else
            crf_step<true><<<gs, bs, 0, stream>>>(src, dst, unary, tpAll,
                                                  s, out);
    }
}

// Round 14
// 612.157 us; speedup vs baseline: 1.4350x; 1.4350x over previous
//
#include <hip/hip_runtime.h>

typedef _Float16 h2 __attribute__((ext_vector_type(2)));

#define HH 480
#define WW 854
#define HWSZ (HH * WW)
#define PAD 192                 // = 3 * max dilation (64)
#define PSTR 1240               // padded row stride
#define PH (HH + 2 * PAD)       // 864
#define PCELLS (PH * PSTR)      // 1,071,360 cells * 8 B per plane
#define TPSTRIDE 240            // floats per step in tp table
#define RS0 (64 * PSTR * 8)     // k0 row step, bytes
#define RS1 (16 * PSTR * 8)     // k1 row step, bytes

#if __has_builtin(__builtin_amdgcn_exp2f)
#define EXP2(x) __builtin_amdgcn_exp2f(x)
#else
#define EXP2(x) exp2f(x)
#endif

__device__ __forceinline__ float fdot2f(h2 a, h2 b, float c)
{
#if __has_builtin(__builtin_amdgcn_fdot2)
    return __builtin_amdgcn_fdot2(a, b, c, false);
#else
    return fmaf((float)a.x, (float)b.x, fmaf((float)a.y, (float)b.y, c));
#endif
}

__device__ __forceinline__ h2 bch2(unsigned u)
{
    union { unsigned u; h2 h; } v; v.u = u; return v.h;
}
__device__ __forceinline__ unsigned h2u(h2 h)
{
    union { h2 h; unsigned u; } v; v.h = h; return v.u;
}
__device__ __forceinline__ unsigned short hbits(_Float16 h)
{
    union { _Float16 h; unsigned short u; } v; v.h = h; return v.u;
}

// ---------------------------------------------------------------------------
// Init both ping-pong planes (rgb f16, pre-scaled; pad = fp16-max sentinel).
// ---------------------------------------------------------------------------
__global__ __launch_bounds__(256) void init_P(
    const float* __restrict__ xrgb, const float* __restrict__ fs,
    uint2* __restrict__ PA, uint2* __restrict__ PB)
{
    int i = blockIdx.x * 256 + threadIdx.x;
    if (i >= PCELLS) return;
    int y = i / PSTR, x = i - y * PSTR;
    int iy = y - PAD, ix = x - PAD;
    uint2 v;
    if (iy >= 0 && iy < HH && ix >= 0 && ix < WW) {
        int p = iy * WW + ix;
        _Float16 rh = (_Float16)(xrgb[p] * (1.0f / fs[2]));
        _Float16 gh = (_Float16)(xrgb[HWSZ + p] * (1.0f / fs[3]));
        _Float16 bh = (_Float16)(xrgb[2 * HWSZ + p] * (1.0f / fs[4]));
        v = make_uint2(h2u(h2{rh, gh}), h2u(h2{bh, (_Float16)0}));
    } else {
        v = make_uint2(0x7BFF7BFFu, 0x00007BFFu);  // sentinel, q=0
    }
    PA[i] = v;
    PB[i] = v;
}

// ---------------------------------------------------------------------------
// Step-0 q merged into plane A.
// ---------------------------------------------------------------------------
__global__ __launch_bounds__(256) void pack0(
    const float* __restrict__ unary, unsigned* __restrict__ PAw)
{
    int i = blockIdx.x * 256 + threadIdx.x;
    if (i >= HWSZ) return;
    float l0 = unary[i], l1 = unary[HWSZ + i];
    float q = 1.0f / (1.0f + __expf(5.0f * (l1 - l0)));
    int y = i / WW, x = i - y * WW;
    int c = (y + PAD) * PSTR + x + PAD;
    unsigned old = PAw[2 * c + 1];
    PAw[2 * c + 1] = (old & 0xFFFFu) | ((unsigned)hbits((_Float16)q) << 16);
}

// ---------------------------------------------------------------------------
// Precompute per-step tap tables + scalars to global (read back via s_load).
// ---------------------------------------------------------------------------
__global__ __launch_bounds__(256) void build_tp(
    const float* __restrict__ fs, const float* __restrict__ uwArr,
    const float* __restrict__ pwArr,
    const float* __restrict__ w0, const float* __restrict__ w1,
    const float* __restrict__ w2,
    const float* __restrict__ c0, const float* __restrict__ c1,
    float* __restrict__ tp)
{
    int s = blockIdx.x;
    int t = threadIdx.x;
    float* d = tp + s * TPSTRIDE;
    const float NH = -0.72134752044448169f;  // -0.5 * log2(e)

    if (t < 49) {                       // kernel 0: 7x7 dil 64
        int dy = t / 7 - 3, dx = t % 7 - 3;
        float py = dy * 64.0f / fs[0], px = dx * 64.0f / fs[1];
        d[(t / 7) * 8 + t % 7] =
            log2f(w0[s * 49 + t]) + NH * (py * py + px * px);
    } else if (t >= 64 && t < 113) {    // kernel 1: 7x7 dil 16
        int u = t - 64;
        int dy = u / 7 - 3, dx = u % 7 - 3;
        float py = dy * 16.0f / fs[5], px = dx * 16.0f / fs[6];
        d[56 + (u / 7) * 8 + u % 7] =
            log2f(w1[s * 49 + u]) + NH * (py * py + px * px);
    } else if (t >= 128 && t < 209) {   // kernel 2: 9x9 dil 1
        int u = t - 128;
        int dy = u / 9 - 4, dx = u % 9 - 4;
        float py = dy / fs[10], px = dx / fs[11];
        d[112 + (u / 9) * 12 + u % 9] =
            log2f(w2[s * 81 + u]) + NH * (py * py + px * px);
    } else if (t == 224) {
        float r1 = fs[2] / fs[7], r2 = fs[2] / fs[12];
        d[220] = NH;
        d[221] = NH * r1 * r1;
        d[222] = NH * r2 * r2;
        d[223] = c0[s * 4 + 0];  d[224] = c0[s * 4 + 1];
        d[225] = c0[s * 4 + 2];  d[226] = c0[s * 4 + 3];
        d[227] = c1[s * 4 + 0];  d[228] = c1[s * 4 + 1];
        d[229] = c1[s * 4 + 2];  d[230] = c1[s * 4 + 3];
        d[231] = pwArr[s * 3 + 0];
        d[232] = pwArr[s * 3 + 1];
        d[233] = pwArr[s * 3 + 2];
        d[234] = uwArr[s] * 5.0f;
    }
}

// ---------------------------------------------------------------------------
// One tap on an 8-B cell (R10-verified arithmetic, 8 issue ops).
// ---------------------------------------------------------------------------
__device__ __forceinline__ void tap8(uint2 aq, h2 rgp, h2 bqp, float nk,
                                     float tpv, float& A, float& B)
{
    h2 drg = bch2(aq.x) - rgp;
    h2 dbq = bch2(aq.y) - bqp;
    float s1 = fdot2f(drg, drg, 0.0f);
    float db = (float)dbq.x;
    float ssq = fmaf(db, db, s1);
    float e = EXP2(fmaf(ssq, nk, tpv));
    A = fmaf(e, (float)bch2(aq.y).y, A);   // q = hi half -> v_fma_mix
    B += e;
}

// Pair tap: one uint4 = two adjacent cells, serves both pixels of the lane.
__device__ __forceinline__ void tapPair(uint4 a, h2 rg0, h2 bq0, h2 rg1, h2 bq1,
                                        float nk, float tpv,
                                        float& Aa, float& Ba, float& Ab, float& Bb)
{
    tap8(make_uint2(a.x, a.y), rg0, bq0, nk, tpv, Aa, Ba);
    tap8(make_uint2(a.z, a.w), rg1, bq1, nk, tpv, Ab, Bb);
}

// Row of 7 paired b128 loads from one base pointer + immediate offsets.
template <int STEPB>
__device__ __forceinline__ void loadRow(uint4 (&b)[7], const char* __restrict__ rb)
{
#pragma unroll
    for (int j = 0; j < 7; ++j)
        b[j] = *(const uint4*)(rb + (j - 3) * STEPB);
}
__device__ __forceinline__ void compRow(const uint4 (&b)[7],
    const float* __restrict__ tprow, h2 rg0, h2 bq0, h2 rg1, h2 bq1, float nk,
    float& Aa, float& Ba, float& Ab, float& Bb)
{
#pragma unroll
    for (int j = 0; j < 7; ++j)
        tapPair(b[j], rg0, bq0, rg1, bq1, nk, tprow[j], Aa, Ba, Ab, Bb);
}

// k2 row from LDS: even dx -> b128 pair read; odd dx -> two b64 reads.
template <int I>
__device__ __forceinline__ void compK2row(const uint4* __restrict__ T2r,
    const uint2* __restrict__ T2r2,
    const float* __restrict__ tp2, h2 rg0, h2 bq0, h2 rg1, h2 bq1, float nk,
    float& Aa, float& Ba, float& Ab, float& Bb)
{
#pragma unroll
    for (int j = 0; j < 9; ++j) {
        float tpv = tp2[I * 12 + j];
        if ((j & 1) == 0) {
            uint4 a = T2r[I * 68 + j / 2];
            tapPair(a, rg0, bq0, rg1, bq1, nk, tpv, Aa, Ba, Ab, Bb);
        } else {
            uint2 c0 = T2r2[I * 136 + j];
            uint2 c1 = T2r2[I * 136 + j + 1];
            tap8(c0, rg0, bq0, nk, tpv, Aa, Ba);
            tap8(c1, rg1, bq1, nk, tpv, Ab, Bb);
        }
    }
}

// ---------------------------------------------------------------------------
// Fused step, PX=2. Block = (64,4) threads covering a 128x4 px tile.
// k0/k1 from global via running row-base pointers + immediate offsets;
// k2 window (13 KB) in LDS. __launch_bounds__(256,2): the w=2 tier maps to
// a 128-VGPR cap on this toolchain (empirical: w=4 -> 64, w=3 -> 84), and
// R11 proved this exact register shape fits 128 with zero spill.
// ---------------------------------------------------------------------------
template <bool LAST>
__global__ __launch_bounds__(256, 2) void crf_step(
    const uint2* __restrict__ srcP, unsigned* __restrict__ dstPw,
    const float* __restrict__ unary, const float* __restrict__ tpAll,
    int step, float* __restrict__ out)
{
    __shared__ uint4 T2[12 * 68];    // 13056 B

    int tx = threadIdx.x, ty = threadIdx.y;
    int tid = ty * 64 + tx;
    int x0 = blockIdx.x * 128, y0 = blockIdx.y * 4;

    // ---- stage T2: rows y0-4 .. y0+7, cols x0-4.. ----
    for (int c = tid; c < 12 * 68; c += 256) {
        int r = c / 68, col = c - r * 68;
        int gy = y0 - 4 + r;
        T2[c] = *(const uint4*)
            (srcP + (gy + PAD) * PSTR + (x0 - 4 + PAD) + 2 * col);
    }

    int px = x0 + 2 * tx;            // even; pair = (px, px+1)
    int y = y0 + ty;
    bool act = (px < WW);
    int p = y * WW + px;
    int pSafe = act ? p : 0;
    int ccell = (y + PAD) * PSTR + px + PAD;
    const uint2* Pc = srcP + ccell;

    const float* tp0 = tpAll + step * TPSTRIDE;
    const float* tp1 = tp0 + 56;
    const float* tp2 = tp0 + 112;
    const float* sc  = tp0 + 220;
    float nk0 = sc[0], nk1 = sc[1], nk2 = sc[2];

    // running row-base pointers (row 0 of each stream)
    const char* rk0 = (const char*)Pc - 3 * RS0;
    const char* rk1 = (const char*)Pc - 3 * RS1;

    // pre-barrier: center pair, unary pairs, first k0/k1 rows in flight
    uint4 cw = *(const uint4*)Pc;
    float2 unc0 = *(const float2*)(unary + pSafe);
    float2 unc1 = *(const float2*)(unary + HWSZ + pSafe);
    uint4 bA[7], bB[7];
    loadRow<512>(bA, rk0);           // k0 row 0
    loadRow<128>(bB, rk1);           // k1 row 0
    __syncthreads();

    h2 rg0 = bch2(cw.x), bq0 = bch2(cw.y);
    h2 rg1 = bch2(cw.z), bq1 = bch2(cw.w);

    const uint4* T2r  = T2 + ty * 68 + tx;
    const uint2* T2r2 = (const uint2*)T2 + ty * 136 + 2 * tx;

    float A0a = 0, B0a = 0, A0b = 0, B0b = 0;
    float A1a = 0, B1a = 0, A1b = 0, B1b = 0;
    float A2a = 0, B2a = 0, A2b = 0, B2b = 0;

#define C0(I) compRow(bA, tp0 + (I) * 8, rg0, bq0, rg1, bq1, nk0, A0a, B0a, A0b, B0b)
#define C1(I) compRow(bB, tp1 + (I) * 8, rg0, bq0, rg1, bq1, nk1, A1a, B1a, A1b, B1b)
#define L0()  rk0 += RS0; loadRow<512>(bA, rk0)
#define L1()  rk1 += RS1; loadRow<128>(bB, rk1)
#define K2(I) compK2row<I>(T2r, T2r2, tp2, rg0, bq0, rg1, bq1, nk2, A2a, B2a, A2b, B2b)

    // compute current row, then immediately refill the buffer; k2 LDS rows
    // interleave as latency cover. Per-kernel accumulation order preserved.
    C0(0);  L0();  K2(0);
    C1(0);  L1();  K2(1);
    C0(1);  L0();  K2(2);
    C1(1);  L1();  K2(3);
    C0(2);  L0();  K2(4);
    C1(2);  L1();  K2(5);
    C0(3);  L0();  K2(6);
    C1(3);  L1();  K2(7);
    C0(4);  L0();  K2(8);
    C1(4);  L1();
    C0(5);  L0();
    C1(5);  L1();
    C0(6);
    C1(6);

#undef C0
#undef C1
#undef L0
#undef L1
#undef K2

    if (!act) return;

    float pw0 = sc[11], pw1 = sc[12], pw2 = sc[13], uw5 = sc[14];

    // px0
    float m01a = B0a - A0a, m11a = B1a - A1a, m21a = B2a - A2a;
    float r00a = sc[3] * A0a + sc[4] * m01a;
    float r01a = sc[5] * A0a + sc[6] * m01a;
    float r10a = sc[7] * A1a + sc[8] * m11a;
    float r11a = sc[9] * A1a + sc[10] * m11a;
    float o0a = uw5 * unc0.x + pw0 * r00a + pw1 * r10a + pw2 * A2a;
    float o1a = uw5 * unc1.x + pw0 * r01a + pw1 * r11a + pw2 * m21a;

    // px1
    float m01b = B0b - A0b, m11b = B1b - A1b, m21b = B2b - A2b;
    float r00b = sc[3] * A0b + sc[4] * m01b;
    float r01b = sc[5] * A0b + sc[6] * m01b;
    float r10b = sc[7] * A1b + sc[8] * m11b;
    float r11b = sc[9] * A1b + sc[10] * m11b;
    float o0b = uw5 * unc0.y + pw0 * r00b + pw1 * r10b + pw2 * A2b;
    float o1b = uw5 * unc1.y + pw0 * r01b + pw1 * r11b + pw2 * m21b;

    if (LAST) {
        *(float2*)(out + p) = make_float2(o0a, o0b);
        *(float2*)(out + HWSZ + p) = make_float2(o1a, o1b);
    } else {
        float qa = 1.0f / (1.0f + __expf(o1a - o0a));
        float qb = 1.0f / (1.0f + __expf(o1b - o0b));
        dstPw[2 * ccell + 1] = (cw.y & 0xFFFFu) |
                               ((unsigned)hbits((_Float16)qa) << 16);
        dstPw[2 * ccell + 3] = (cw.w & 0xFFFFu) |
                               ((unsigned)hbits((_Float16)qb) << 16);
    }
}

// ---------------------------------------------------------------------------
extern "C" void kernel_launch(void* const* d_in, const int* in_sizes, int n_in,
                              void* d_out, int out_size, void* d_ws, size_t ws_size,
                              hipStream_t stream)
{
    const float* unary = (const float*)d_in[0];
    const float* xrgb  = (const float*)d_in[1];
    const float* fs    = (const float*)d_in[2];
    // d_in[3] = potts_w (dead in reference forward)
    const float* uw    = (const float*)d_in[4];
    const float* pw    = (const float*)d_in[5];
    const float* w0    = (const float*)d_in[6];
    const float* w1    = (const float*)d_in[7];
    const float* w2    = (const float*)d_in[8];
    const float* c0    = (const float*)d_in[9];
    const float* c1    = (const float*)d_in[10];
    float* out = (float*)d_out;

    uint2* PA = (uint2*)d_ws;                               // 8.57 MB
    uint2* PB = (uint2*)((char*)d_ws + (size_t)PCELLS * 8); // 8.57 MB
    float* tpAll = (float*)((char*)d_ws + (size_t)PCELLS * 16);

    init_P<<<(PCELLS + 255) / 256, 256, 0, stream>>>(xrgb, fs, PA, PB);
    pack0<<<(HWSZ + 255) / 256, 256, 0, stream>>>(unary, (unsigned*)PA);
    build_tp<<<5, 256, 0, stream>>>(fs, uw, pw, w0, w1, w2, c0, c1, tpAll);

    dim3 gs((WW + 127) / 128, HH / 4), bs(64, 4);
    for (int s = 0; s < 5; ++s) {
        const uint2* src = (s & 1) ? PB : PA;
        unsigned* dst = (unsigned*)((s & 1) ? PA : PB);
        if (s < 4)
            crf_step<false><<<gs, bs, 0, stream>>>(src, dst, unary, tpAll,
                                                   s, out);
        else
            crf_step<true><<<gs, bs, 0, stream>>>(src, dst, unary, tpAll,
                                                  s, out);
    }
}

// Round 15
// 340.398 us; speedup vs baseline: 2.5806x; 1.7984x over previous
//
#include <hip/hip_runtime.h>

typedef _Float16 h2 __attribute__((ext_vector_type(2)));

#define HH 480
#define WW 854
#define HWSZ (HH * WW)
#define PAD 192                 // = 3 * max dilation (64)
#define PSTR 1240               // padded row stride
#define PH (HH + 2 * PAD)       // 864
#define PCELLS (PH * PSTR)      // 1,071,360 cells * 8 B per plane
#define TPSTRIDE 240            // floats per step in tp table
#define RS0 (64 * PSTR * 8)     // k0 row step, bytes
#define RS1 (16 * PSTR * 8)     // k1 row step, bytes

#if __has_builtin(__builtin_amdgcn_exp2f)
#define EXP2(x) __builtin_amdgcn_exp2f(x)
#else
#define EXP2(x) exp2f(x)
#endif

__device__ __forceinline__ float fdot2f(h2 a, h2 b, float c)
{
#if __has_builtin(__builtin_amdgcn_fdot2)
    return __builtin_amdgcn_fdot2(a, b, c, false);
#else
    return fmaf((float)a.x, (float)b.x, fmaf((float)a.y, (float)b.y, c));
#endif
}

__device__ __forceinline__ h2 bch2(unsigned u)
{
    union { unsigned u; h2 h; } v; v.u = u; return v.h;
}
__device__ __forceinline__ unsigned h2u(h2 h)
{
    union { h2 h; unsigned u; } v; v.h = h; return v.u;
}
__device__ __forceinline__ unsigned short hbits(_Float16 h)
{
    union { _Float16 h; unsigned short u; } v; v.h = h; return v.u;
}

// ---------------------------------------------------------------------------
// Init both ping-pong planes (rgb f16 pre-scaled; pad = fp16-max sentinel).
// Step-0 q (softmax of 5*unary) fused into plane A.
// ---------------------------------------------------------------------------
__global__ __launch_bounds__(256) void init_P(
    const float* __restrict__ xrgb, const float* __restrict__ unary,
    const float* __restrict__ fs,
    uint2* __restrict__ PA, uint2* __restrict__ PB)
{
    int i = blockIdx.x * 256 + threadIdx.x;
    if (i >= PCELLS) return;
    int y = i / PSTR, x = i - y * PSTR;
    int iy = y - PAD, ix = x - PAD;
    uint2 v, vA;
    if (iy >= 0 && iy < HH && ix >= 0 && ix < WW) {
        int p = iy * WW + ix;
        _Float16 rh = (_Float16)(xrgb[p] * (1.0f / fs[2]));
        _Float16 gh = (_Float16)(xrgb[HWSZ + p] * (1.0f / fs[3]));
        _Float16 bh = (_Float16)(xrgb[2 * HWSZ + p] * (1.0f / fs[4]));
        float l0 = unary[p], l1 = unary[HWSZ + p];
        float q = 1.0f / (1.0f + __expf(5.0f * (l1 - l0)));
        unsigned rg = h2u(h2{rh, gh});
        v = make_uint2(rg, h2u(h2{bh, (_Float16)0}));
        vA = make_uint2(rg, h2u(h2{bh, (_Float16)q}));
    } else {
        v = make_uint2(0x7BFF7BFFu, 0x00007BFFu);  // sentinel, q=0
        vA = v;
    }
    PA[i] = vA;
    PB[i] = v;
}

// ---------------------------------------------------------------------------
// Precompute per-step tap tables + scalars to global (read back via s_load).
// ---------------------------------------------------------------------------
__global__ __launch_bounds__(256) void build_tp(
    const float* __restrict__ fs, const float* __restrict__ uwArr,
    const float* __restrict__ pwArr,
    const float* __restrict__ w0, const float* __restrict__ w1,
    const float* __restrict__ w2,
    const float* __restrict__ c0, const float* __restrict__ c1,
    float* __restrict__ tp)
{
    int s = blockIdx.x;
    int t = threadIdx.x;
    float* d = tp + s * TPSTRIDE;
    const float NH = -0.72134752044448169f;  // -0.5 * log2(e)

    if (t < 49) {                       // kernel 0: 7x7 dil 64
        int dy = t / 7 - 3, dx = t % 7 - 3;
        float py = dy * 64.0f / fs[0], px = dx * 64.0f / fs[1];
        d[(t / 7) * 8 + t % 7] =
            log2f(w0[s * 49 + t]) + NH * (py * py + px * px);
    } else if (t >= 64 && t < 113) {    // kernel 1: 7x7 dil 16
        int u = t - 64;
        int dy = u / 7 - 3, dx = u % 7 - 3;
        float py = dy * 16.0f / fs[5], px = dx * 16.0f / fs[6];
        d[56 + (u / 7) * 8 + u % 7] =
            log2f(w1[s * 49 + u]) + NH * (py * py + px * px);
    } else if (t >= 128 && t < 209) {   // kernel 2: 9x9 dil 1
        int u = t - 128;
        int dy = u / 9 - 4, dx = u % 9 - 4;
        float py = dy / fs[10], px = dx / fs[11];
        d[112 + (u / 9) * 12 + u % 9] =
            log2f(w2[s * 81 + u]) + NH * (py * py + px * px);
    } else if (t == 224) {
        float r1 = fs[2] / fs[7], r2 = fs[2] / fs[12];
        d[220] = NH;
        d[221] = NH * r1 * r1;
        d[222] = NH * r2 * r2;
        d[223] = c0[s * 4 + 0];  d[224] = c0[s * 4 + 1];
        d[225] = c0[s * 4 + 2];  d[226] = c0[s * 4 + 3];
        d[227] = c1[s * 4 + 0];  d[228] = c1[s * 4 + 1];
        d[229] = c1[s * 4 + 2];  d[230] = c1[s * 4 + 3];
        d[231] = pwArr[s * 3 + 0];
        d[232] = pwArr[s * 3 + 1];
        d[233] = pwArr[s * 3 + 2];
        d[234] = uwArr[s] * 5.0f;
    }
}

// ---------------------------------------------------------------------------
// One tap on an 8-B cell (R10-verified arithmetic, 8 issue ops).
// ---------------------------------------------------------------------------
__device__ __forceinline__ void tap8(uint2 aq, h2 rgp, h2 bqp, float nk,
                                     float tpv, float& A, float& B)
{
    h2 drg = bch2(aq.x) - rgp;
    h2 dbq = bch2(aq.y) - bqp;
    float s1 = fdot2f(drg, drg, 0.0f);
    float db = (float)dbq.x;
    float ssq = fmaf(db, db, s1);
    float e = EXP2(fmaf(ssq, nk, tpv));
    A = fmaf(e, (float)bch2(aq.y).y, A);   // q = hi half -> v_fma_mix
    B += e;
}

// Pair tap: one uint4 = two adjacent cells, serves both pixels of the lane.
__device__ __forceinline__ void tapPair(uint4 a, h2 rg0, h2 bq0, h2 rg1, h2 bq1,
                                        float nk, float tpv,
                                        float& Aa, float& Ba, float& Ab, float& Bb)
{
    tap8(make_uint2(a.x, a.y), rg0, bq0, nk, tpv, Aa, Ba);
    tap8(make_uint2(a.z, a.w), rg1, bq1, nk, tpv, Ab, Bb);
}

// Row of 7 paired b128 loads from one base pointer + immediate offsets.
template <int STEPB>
__device__ __forceinline__ void loadRow(uint4 (&b)[7], const char* __restrict__ rb)
{
#pragma unroll
    for (int j = 0; j < 7; ++j)
        b[j] = *(const uint4*)(rb + (j - 3) * STEPB);
}
__device__ __forceinline__ void compRow(const uint4 (&b)[7],
    const float* __restrict__ tprow, h2 rg0, h2 bq0, h2 rg1, h2 bq1, float nk,
    float& Aa, float& Ba, float& Ab, float& Bb)
{
#pragma unroll
    for (int j = 0; j < 7; ++j)
        tapPair(b[j], rg0, bq0, rg1, bq1, nk, tprow[j], Aa, Ba, Ab, Bb);
}

// k2 row from LDS (runtime row index): even dx -> b128; odd dx -> 2x b64.
__device__ __forceinline__ void compK2row(int I,
    const uint4* __restrict__ T2r, const uint2* __restrict__ T2r2,
    const float* __restrict__ tp2, h2 rg0, h2 bq0, h2 rg1, h2 bq1, float nk,
    float& Aa, float& Ba, float& Ab, float& Bb)
{
#pragma unroll
    for (int j = 0; j < 9; ++j) {
        float tpv = tp2[I * 12 + j];
        if ((j & 1) == 0) {
            uint4 a = T2r[I * 68 + j / 2];
            tapPair(a, rg0, bq0, rg1, bq1, nk, tpv, Aa, Ba, Ab, Bb);
        } else {
            uint2 c0 = T2r2[I * 136 + j];
            uint2 c1 = T2r2[I * 136 + j + 1];
            tap8(c0, rg0, bq0, nk, tpv, Aa, Ba);
            tap8(c1, rg1, bq1, nk, tpv, Ab, Bb);
        }
    }
}

// ---------------------------------------------------------------------------
// Fused step, PX=2, minimal live state: ONE 7xuint4 buffer, load-row ->
// consume-row (no cross-row prefetch). k2 window (13 KB) in LDS. No VGPR
// cap: peak demand ~80 regs by construction, allocator decides freely.
// ---------------------------------------------------------------------------
template <bool LAST>
__global__ __launch_bounds__(256) void crf_step(
    const uint2* __restrict__ srcP, unsigned* __restrict__ dstPw,
    const float* __restrict__ unary, const float* __restrict__ tpAll,
    int step, float* __restrict__ out)
{
    __shared__ uint4 T2[12 * 68];    // 13056 B

    int tx = threadIdx.x, ty = threadIdx.y;
    int tid = ty * 64 + tx;
    int x0 = blockIdx.x * 128, y0 = blockIdx.y * 4;

    // ---- stage T2: rows y0-4 .. y0+7, cols x0-4.. ----
    for (int c = tid; c < 12 * 68; c += 256) {
        int r = c / 68, col = c - r * 68;
        int gy = y0 - 4 + r;
        T2[c] = *(const uint4*)
            (srcP + (gy + PAD) * PSTR + (x0 - 4 + PAD) + 2 * col);
    }

    int px = x0 + 2 * tx;            // even; pair = (px, px+1)
    int y = y0 + ty;
    bool act = (px < WW);
    int p = y * WW + px;
    int pSafe = act ? p : 0;
    int ccell = (y + PAD) * PSTR + px + PAD;
    const uint2* Pc = srcP + ccell;

    const float* tp0 = tpAll + step * TPSTRIDE;
    const float* tp1 = tp0 + 56;
    const float* tp2 = tp0 + 112;
    const float* sc  = tp0 + 220;
    float nk0 = sc[0], nk1 = sc[1], nk2 = sc[2];

    uint4 cw = *(const uint4*)Pc;
    float2 unc0 = *(const float2*)(unary + pSafe);
    float2 unc1 = *(const float2*)(unary + HWSZ + pSafe);
    __syncthreads();

    h2 rg0 = bch2(cw.x), bq0 = bch2(cw.y);
    h2 rg1 = bch2(cw.z), bq1 = bch2(cw.w);

    const uint4* T2r  = T2 + ty * 68 + tx;
    const uint2* T2r2 = (const uint2*)T2 + ty * 136 + 2 * tx;

    float A0a = 0, B0a = 0, A0b = 0, B0b = 0;
    float A1a = 0, B1a = 0, A1b = 0, B1b = 0;
    float A2a = 0, B2a = 0, A2b = 0, B2b = 0;

    const char* rk0 = (const char*)Pc - 3 * RS0;
    const char* rk1 = (const char*)Pc - 3 * RS1;
    uint4 buf[7];

#pragma unroll
    for (int i = 0; i < 7; ++i) {
        loadRow<512>(buf, rk0); rk0 += RS0;
        // k2 row i from LDS covers the k0 row's global latency
        compK2row(i, T2r, T2r2, tp2, rg0, bq0, rg1, bq1, nk2,
                  A2a, B2a, A2b, B2b);
        compRow(buf, tp0 + i * 8, rg0, bq0, rg1, bq1, nk0,
                A0a, B0a, A0b, B0b);
        loadRow<128>(buf, rk1); rk1 += RS1;
        compRow(buf, tp1 + i * 8, rg0, bq0, rg1, bq1, nk1,
                A1a, B1a, A1b, B1b);
    }
    compK2row(7, T2r, T2r2, tp2, rg0, bq0, rg1, bq1, nk2, A2a, B2a, A2b, B2b);
    compK2row(8, T2r, T2r2, tp2, rg0, bq0, rg1, bq1, nk2, A2a, B2a, A2b, B2b);

    if (!act) return;

    float pw0 = sc[11], pw1 = sc[12], pw2 = sc[13], uw5 = sc[14];

    // px0
    float m01a = B0a - A0a, m11a = B1a - A1a, m21a = B2a - A2a;
    float r00a = sc[3] * A0a + sc[4] * m01a;
    float r01a = sc[5] * A0a + sc[6] * m01a;
    float r10a = sc[7] * A1a + sc[8] * m11a;
    float r11a = sc[9] * A1a + sc[10] * m11a;
    float o0a = uw5 * unc0.x + pw0 * r00a + pw1 * r10a + pw2 * A2a;
    float o1a = uw5 * unc1.x + pw0 * r01a + pw1 * r11a + pw2 * m21a;

    // px1
    float m01b = B0b - A0b, m11b = B1b - A1b, m21b = B2b - A2b;
    float r00b = sc[3] * A0b + sc[4] * m01b;
    float r01b = sc[5] * A0b + sc[6] * m01b;
    float r10b = sc[7] * A1b + sc[8] * m11b;
    float r11b = sc[9] * A1b + sc[10] * m11b;
    float o0b = uw5 * unc0.y + pw0 * r00b + pw1 * r10b + pw2 * A2b;
    float o1b = uw5 * unc1.y + pw0 * r01b + pw1 * r11b + pw2 * m21b;

    if (LAST) {
        *(float2*)(out + p) = make_float2(o0a, o0b);
        *(float2*)(out + HWSZ + p) = make_float2(o1a, o1b);
    } else {
        float qa = 1.0f / (1.0f + __expf(o1a - o0a));
        float qb = 1.0f / (1.0f + __expf(o1b - o0b));
        dstPw[2 * ccell + 1] = (cw.y & 0xFFFFu) |
                               ((unsigned)hbits((_Float16)qa) << 16);
        dstPw[2 * ccell + 3] = (cw.w & 0xFFFFu) |
                               ((unsigned)hbits((_Float16)qb) << 16);
    }
}

// ---------------------------------------------------------------------------
extern "C" void kernel_launch(void* const* d_in, const int* in_sizes, int n_in,
                              void* d_out, int out_size, void* d_ws, size_t ws_size,
                              hipStream_t stream)
{
    const float* unary = (const float*)d_in[0];
    const float* xrgb  = (const float*)d_in[1];
    const float* fs    = (const float*)d_in[2];
    // d_in[3] = potts_w (dead in reference forward)
    const float* uw    = (const float*)d_in[4];
    const float* pw    = (const float*)d_in[5];
    const float* w0    = (const float*)d_in[6];
    const float* w1    = (const float*)d_in[7];
    const float* w2    = (const float*)d_in[8];
    const float* c0    = (const float*)d_in[9];
    const float* c1    = (const float*)d_in[10];
    float* out = (float*)d_out;

    uint2* PA = (uint2*)d_ws;                               // 8.57 MB
    uint2* PB = (uint2*)((char*)d_ws + (size_t)PCELLS * 8); // 8.57 MB
    float* tpAll = (float*)((char*)d_ws + (size_t)PCELLS * 16);

    init_P<<<(PCELLS + 255) / 256, 256, 0, stream>>>(xrgb, unary, fs, PA, PB);
    build_tp<<<5, 256, 0, stream>>>(fs, uw, pw, w0, w1, w2, c0, c1, tpAll);

    dim3 gs((WW + 127) / 128, HH / 4), bs(64, 4);
    for (int s = 0; s < 5; ++s) {
        const uint2* src = (s & 1) ? PB : PA;
        unsigned* dst = (unsigned*)((s & 1) ? PA : PB);
        if (s < 4)
            crf_step<false><<<gs, bs, 0, stream>>>(src, dst, unary, tpAll,
                                                   s, out);
        else
            crf_step<true><<<gs, bs, 0, stream>>>(src, dst, unary, tpAll,
                                                  s, out);
    }
}

// Round 16
// 165.377 us; speedup vs baseline: 5.3116x; 2.0583x over previous
//
#include <hip/hip_runtime.h>

typedef _Float16 h2 __attribute__((ext_vector_type(2)));

#define HH 480
#define WW 854
#define HWSZ (HH * WW)
#define PAD 192                 // = 3 * max dilation (64)
#define PSTR 1240               // padded row stride
#define PH (HH + 2 * PAD)       // 864
#define PCELLS (PH * PSTR)      // 1,071,360 cells * 8 B per plane
#define TPSTRIDE 240            // floats per step in tp table

#if __has_builtin(__builtin_amdgcn_exp2f)
#define EXP2(x) __builtin_amdgcn_exp2f(x)
#else
#define EXP2(x) exp2f(x)
#endif

__device__ __forceinline__ float fdot2f(h2 a, h2 b, float c)
{
#if __has_builtin(__builtin_amdgcn_fdot2)
    return __builtin_amdgcn_fdot2(a, b, c, false);
#else
    return fmaf((float)a.x, (float)b.x, fmaf((float)a.y, (float)b.y, c));
#endif
}

__device__ __forceinline__ h2 bch2(unsigned u)
{
    union { unsigned u; h2 h; } v; v.u = u; return v.h;
}
__device__ __forceinline__ unsigned h2u(h2 h)
{
    union { h2 h; unsigned u; } v; v.h = h; return v.u;
}
__device__ __forceinline__ unsigned short hbits(_Float16 h)
{
    union { _Float16 h; unsigned short u; } v; v.h = h; return v.u;
}

// ---------------------------------------------------------------------------
// Init both ping-pong planes (rgb f16 pre-scaled; pad = fp16-max sentinel).
// Step-0 q (softmax of 5*unary) fused into plane A (verified in R15).
// ---------------------------------------------------------------------------
__global__ __launch_bounds__(256) void init_P(
    const float* __restrict__ xrgb, const float* __restrict__ unary,
    const float* __restrict__ fs,
    uint2* __restrict__ PA, uint2* __restrict__ PB)
{
    int i = blockIdx.x * 256 + threadIdx.x;
    if (i >= PCELLS) return;
    int y = i / PSTR, x = i - y * PSTR;
    int iy = y - PAD, ix = x - PAD;
    uint2 v, vA;
    if (iy >= 0 && iy < HH && ix >= 0 && ix < WW) {
        int p = iy * WW + ix;
        _Float16 rh = (_Float16)(xrgb[p] * (1.0f / fs[2]));
        _Float16 gh = (_Float16)(xrgb[HWSZ + p] * (1.0f / fs[3]));
        _Float16 bh = (_Float16)(xrgb[2 * HWSZ + p] * (1.0f / fs[4]));
        float l0 = unary[p], l1 = unary[HWSZ + p];
        float q = 1.0f / (1.0f + __expf(5.0f * (l1 - l0)));
        unsigned rg = h2u(h2{rh, gh});
        v = make_uint2(rg, h2u(h2{bh, (_Float16)0}));
        vA = make_uint2(rg, h2u(h2{bh, (_Float16)q}));
    } else {
        v = make_uint2(0x7BFF7BFFu, 0x00007BFFu);  // sentinel, q=0
        vA = v;
    }
    PA[i] = vA;
    PB[i] = v;
}

// ---------------------------------------------------------------------------
// Precompute per-step tap tables + scalars to global (read back via s_load).
// Per step (TPSTRIDE floats): [0..55] tp0, [56..111] tp1, [112..219] tp2,
// [220..234] scal = {nk0,nk1,nk2, c0[4], c1[4], pw[3], uw5}.
// ---------------------------------------------------------------------------
__global__ __launch_bounds__(256) void build_tp(
    const float* __restrict__ fs, const float* __restrict__ uwArr,
    const float* __restrict__ pwArr,
    const float* __restrict__ w0, const float* __restrict__ w1,
    const float* __restrict__ w2,
    const float* __restrict__ c0, const float* __restrict__ c1,
    float* __restrict__ tp)
{
    int s = blockIdx.x;
    int t = threadIdx.x;
    float* d = tp + s * TPSTRIDE;
    const float NH = -0.72134752044448169f;  // -0.5 * log2(e)

    if (t < 49) {                       // kernel 0: 7x7 dil 64
        int dy = t / 7 - 3, dx = t % 7 - 3;
        float py = dy * 64.0f / fs[0], px = dx * 64.0f / fs[1];
        d[(t / 7) * 8 + t % 7] =
            log2f(w0[s * 49 + t]) + NH * (py * py + px * px);
    } else if (t >= 64 && t < 113) {    // kernel 1: 7x7 dil 16
        int u = t - 64;
        int dy = u / 7 - 3, dx = u % 7 - 3;
        float py = dy * 16.0f / fs[5], px = dx * 16.0f / fs[6];
        d[56 + (u / 7) * 8 + u % 7] =
            log2f(w1[s * 49 + u]) + NH * (py * py + px * px);
    } else if (t >= 128 && t < 209) {   // kernel 2: 9x9 dil 1
        int u = t - 128;
        int dy = u / 9 - 4, dx = u % 9 - 4;
        float py = dy / fs[10], px = dx / fs[11];
        d[112 + (u / 9) * 12 + u % 9] =
            log2f(w2[s * 81 + u]) + NH * (py * py + px * px);
    } else if (t == 224) {
        float r1 = fs[2] / fs[7], r2 = fs[2] / fs[12];
        d[220] = NH;
        d[221] = NH * r1 * r1;
        d[222] = NH * r2 * r2;
        d[223] = c0[s * 4 + 0];  d[224] = c0[s * 4 + 1];
        d[225] = c0[s * 4 + 2];  d[226] = c0[s * 4 + 3];
        d[227] = c1[s * 4 + 0];  d[228] = c1[s * 4 + 1];
        d[229] = c1[s * 4 + 2];  d[230] = c1[s * 4 + 3];
        d[231] = pwArr[s * 3 + 0];
        d[232] = pwArr[s * 3 + 1];
        d[233] = pwArr[s * 3 + 2];
        d[234] = uwArr[s] * 5.0f;
    }
}

// ---------------------------------------------------------------------------
// One tap on an 8-B cell (R10-verified arithmetic, 8 issue ops).
// ---------------------------------------------------------------------------
__device__ __forceinline__ void tap8(uint2 aq, h2 rgp, h2 bqp, float nk,
                                     float tpv, float& A, float& B)
{
    h2 drg = bch2(aq.x) - rgp;
    h2 dbq = bch2(aq.y) - bqp;
    float s1 = fdot2f(drg, drg, 0.0f);
    float db = (float)dbq.x;
    float ssq = fmaf(db, db, s1);
    float e = EXP2(fmaf(ssq, nk, tpv));
    A = fmaf(e, (float)bch2(aq.y).y, A);   // q = hi half -> v_fma_mix
    B += e;
}

// k0 chunk helpers: static indices only (full unroll).
template <int T0, int N>
__device__ __forceinline__ void loadK0(uint2 (&buf)[N], const uint2* __restrict__ Pc)
{
#pragma unroll
    for (int t = 0; t < N; ++t) {
        const int tt = T0 + t;
        buf[t] = Pc[(tt / 7 - 3) * 64 * PSTR + (tt % 7 - 3) * 64];
    }
}
template <int T0, int N>
__device__ __forceinline__ void compK0(const uint2 (&buf)[N],
                                       const float* __restrict__ tp0,
                                       h2 rgp, h2 bqp, float nk,
                                       float& A, float& B)
{
#pragma unroll
    for (int t = 0; t < N; ++t) {
        const int tt = T0 + t;
        tap8(buf[t], rgp, bqp, nk, tp0[(tt / 7) * 8 + tt % 7], A, B);
    }
}
// k1 chunk from LDS.
template <int T0, int N>
__device__ __forceinline__ void compK1(const uint2* __restrict__ T1b,
                                       const float* __restrict__ tp1,
                                       h2 rgp, h2 bqp, float nk,
                                       float& A, float& B)
{
#pragma unroll
    for (int t = 0; t < N; ++t) {
        const int tt = T0 + t;
        tap8(T1b[(tt / 7) * 448 + (tt % 7) * 16], rgp, bqp, nk,
             tp1[(tt / 7) * 8 + tt % 7], A, B);
    }
}
// k2 chunk from LDS.
template <int T0, int N>
__device__ __forceinline__ void compK2(const uint2* __restrict__ T2b,
                                       const float* __restrict__ tp2,
                                       h2 rgp, h2 bqp, float nk,
                                       float& A, float& B)
{
#pragma unroll
    for (int t = 0; t < N; ++t) {
        const int tt = T0 + t;
        tap8(T2b[(tt / 9) * 136 + tt % 9], rgp, bqp, nk,
             tp2[(tt / 9) * 12 + tt % 9], A, B);
    }
}

// ---------------------------------------------------------------------------
// Fused step (R10-proven). Block = 128x2. k1/k2 from LDS tiles, k0 4-chunk
// reg-prefetched (chunk A issued pre-barrier), constants via uniform s_load.
// Non-last steps write only q' (1 dword) to the ping-pong plane.
// ---------------------------------------------------------------------------
template <bool LAST>
__global__ __launch_bounds__(256, 4) void crf_step(
    const uint2* __restrict__ srcP, unsigned* __restrict__ dstPw,
    const float* __restrict__ unary, const float* __restrict__ tpAll,
    int step, float* __restrict__ out)
{
    __shared__ uint2 T1[14 * 224];   // k1 tile: 25088 B
    __shared__ uint2 T2[10 * 136];   // k2 tile: 10880 B

    int tid = threadIdx.y * 128 + threadIdx.x;
    int x0 = blockIdx.x * 128, y0 = blockIdx.y * 2;

    // ---- stage k1 tile (waves 0-1) and k2 tile (waves 2-3) concurrently ----
#pragma unroll
    for (int r = 0; r < 14; ++r) {
        if (tid < 112) {
            int gy = y0 + 16 * (r >> 1) + (r & 1) - 48;
            const uint4* srow = (const uint4*)
                (srcP + (gy + PAD) * PSTR + (x0 - 48 + PAD));
            ((uint4*)T1)[r * 112 + tid] = srow[tid];
        }
    }
#pragma unroll
    for (int r = 0; r < 10; ++r) {
        int t2 = tid - 128;
        if (t2 >= 0 && t2 < 68) {
            int gy = y0 - 4 + r;
            const uint4* srow = (const uint4*)
                (srcP + (gy + PAD) * PSTR + (x0 - 4 + PAD));
            ((uint4*)T2)[r * 68 + t2] = srow[t2];
        }
    }

    int x = x0 + threadIdx.x;
    int y = y0 + threadIdx.y;
    int p = y * WW + x;
    int ccell = (y + PAD) * PSTR + x + PAD;

    // uniform tables -> s_load (issue early, independent of staging)
    const float* tp0 = tpAll + step * TPSTRIDE;
    const float* tp1 = tp0 + 56;
    const float* tp2 = tp0 + 112;
    const float* sc  = tp0 + 220;
    float nk0 = sc[0], nk1 = sc[1], nk2 = sc[2];

    const uint2* Pc = srcP + ccell;
    uint2 cw = make_uint2(0u, 0u);
    float un0 = 0.f, un1 = 0.f;
    uint2 bA[13];
    bool act = (x < WW);
    if (act) {
        cw = *Pc;
        un0 = unary[p]; un1 = unary[HWSZ + p];
        loadK0<0, 13>(bA, Pc);       // chunk A in flight across the barrier
    }
    __syncthreads();
    if (!act) return;

    h2 rgp = bch2(cw.x);
    h2 bqp = bch2(cw.y);

    const uint2* T1b = T1 + threadIdx.y * 224 + threadIdx.x;
    const uint2* T2b = T2 + threadIdx.y * 136 + threadIdx.x;

    float A0 = 0.f, B0 = 0.f, A1 = 0.f, B1 = 0.f, A2 = 0.f, B2 = 0.f;

    // ---- k0 register pipeline interleaved with k1/k2 LDS compute ----
    uint2 bB[12], bC[12], bD[12];
    loadK0<13, 12>(bB, Pc);
    compK2<0, 20>(T2b, tp2, rgp, bqp, nk2, A2, B2);
    compK0<0, 13>(bA, tp0, rgp, bqp, nk0, A0, B0);
    loadK0<25, 12>(bC, Pc);
    compK2<20, 20>(T2b, tp2, rgp, bqp, nk2, A2, B2);
    compK0<13, 12>(bB, tp0, rgp, bqp, nk0, A0, B0);
    loadK0<37, 12>(bD, Pc);
    compK1<0, 25>(T1b, tp1, rgp, bqp, nk1, A1, B1);
    compK0<25, 12>(bC, tp0, rgp, bqp, nk0, A0, B0);
    compK2<40, 20>(T2b, tp2, rgp, bqp, nk2, A2, B2);
    compK0<37, 12>(bD, tp0, rgp, bqp, nk0, A0, B0);
    compK1<25, 24>(T1b, tp1, rgp, bqp, nk1, A1, B1);
    compK2<60, 21>(T2b, tp2, rgp, bqp, nk2, A2, B2);

    float m00 = A0, m01 = B0 - A0;
    float m10 = A1, m11 = B1 - A1;
    float m20 = A2, m21 = B2 - A2;

    float r00 = sc[3] * m00 + sc[4] * m01;
    float r01 = sc[5] * m00 + sc[6] * m01;
    float r10 = sc[7] * m10 + sc[8] * m11;
    float r11 = sc[9] * m10 + sc[10] * m11;

    float pw0 = sc[11], pw1 = sc[12], pw2 = sc[13], uw5 = sc[14];
    float o0 = uw5 * un0 + pw0 * r00 + pw1 * r10 + pw2 * m20;
    float o1 = uw5 * un1 + pw0 * r01 + pw1 * r11 + pw2 * m21;

    if (LAST) {
        out[p] = o0;
        out[HWSZ + p] = o1;
    } else {
        float qn = 1.0f / (1.0f + __expf(o1 - o0));
        unsigned nb = (h2u(bqp) & 0xFFFFu) |
                      ((unsigned)hbits((_Float16)qn) << 16);
        dstPw[2 * ccell + 1] = nb;
    }
}

// ---------------------------------------------------------------------------
extern "C" void kernel_launch(void* const* d_in, const int* in_sizes, int n_in,
                              void* d_out, int out_size, void* d_ws, size_t ws_size,
                              hipStream_t stream)
{
    const float* unary = (const float*)d_in[0];
    const float* xrgb  = (const float*)d_in[1];
    const float* fs    = (const float*)d_in[2];
    // d_in[3] = potts_w (dead in reference forward)
    const float* uw    = (const float*)d_in[4];
    const float* pw    = (const float*)d_in[5];
    const float* w0    = (const float*)d_in[6];
    const float* w1    = (const float*)d_in[7];
    const float* w2    = (const float*)d_in[8];
    const float* c0    = (const float*)d_in[9];
    const float* c1    = (const float*)d_in[10];
    float* out = (float*)d_out;

    uint2* PA = (uint2*)d_ws;                               // 8.57 MB
    uint2* PB = (uint2*)((char*)d_ws + (size_t)PCELLS * 8); // 8.57 MB
    float* tpAll = (float*)((char*)d_ws + (size_t)PCELLS * 16);

    init_P<<<(PCELLS + 255) / 256, 256, 0, stream>>>(xrgb, unary, fs, PA, PB);
    build_tp<<<5, 256, 0, stream>>>(fs, uw, pw, w0, w1, w2, c0, c1, tpAll);

    dim3 gs((WW + 127) / 128, HH / 2), bs(128, 2);
    for (int s = 0; s < 5; ++s) {
        const uint2* src = (s & 1) ? PB : PA;
        unsigned* dst = (unsigned*)((s & 1) ? PA : PB);
        if (s < 4)
            crf_step<false><<<gs, bs, 0, stream>>>(src, dst, unary, tpAll,
                                                   s, out);
        else
            crf_step<true><<<gs, bs, 0, stream>>>(src, dst, unary, tpAll,
                                                  s, out);
    }
}

// Round 17
// 162.738 us; speedup vs baseline: 5.3978x; 1.0162x over previous
//
#include <hip/hip_runtime.h>

typedef _Float16 h2 __attribute__((ext_vector_type(2)));

#define HH 480
#define WW 854
#define HWSZ (HH * WW)
#define PAD 192                 // = 3 * max dilation (64)
#define PSTR 1240               // padded row stride
#define PH (HH + 2 * PAD)       // 864
#define PCELLS (PH * PSTR)      // 1,071,360 cells * 8 B per plane
#define TPSTRIDE 240            // floats per step in tp table

#if __has_builtin(__builtin_amdgcn_exp2f)
#define EXP2(x) __builtin_amdgcn_exp2f(x)
#else
#define EXP2(x) exp2f(x)
#endif

__device__ __forceinline__ float fdot2f(h2 a, h2 b, float c)
{
#if __has_builtin(__builtin_amdgcn_fdot2)
    return __builtin_amdgcn_fdot2(a, b, c, false);
#else
    return fmaf((float)a.x, (float)b.x, fmaf((float)a.y, (float)b.y, c));
#endif
}

__device__ __forceinline__ h2 bch2(unsigned u)
{
    union { unsigned u; h2 h; } v; v.u = u; return v.h;
}
__device__ __forceinline__ unsigned h2u(h2 h)
{
    union { h2 h; unsigned u; } v; v.h = h; return v.u;
}
__device__ __forceinline__ unsigned short hbits(_Float16 h)
{
    union { _Float16 h; unsigned short u; } v; v.h = h; return v.u;
}

// ---------------------------------------------------------------------------
// Fused setup: (1) per-step tap tables + scalars (first 5 blocks);
// (2) init both ping-pong planes, TWO cells per thread (uint4 stores).
// rgb f16 pre-scaled; pad = fp16-max sentinel; step-0 q fused into plane A.
// ---------------------------------------------------------------------------
__global__ __launch_bounds__(256) void init_all(
    const float* __restrict__ xrgb, const float* __restrict__ unary,
    const float* __restrict__ fs, const float* __restrict__ uwArr,
    const float* __restrict__ pwArr,
    const float* __restrict__ w0, const float* __restrict__ w1,
    const float* __restrict__ w2,
    const float* __restrict__ c0, const float* __restrict__ c1,
    uint4* __restrict__ PA4, uint4* __restrict__ PB4,
    float* __restrict__ tp)
{
    const float NH = -0.72134752044448169f;  // -0.5 * log2(e)

    if (blockIdx.x < 5) {   // ---- build_tp part ----
        int s = blockIdx.x;
        int t = threadIdx.x;
        float* d = tp + s * TPSTRIDE;
        if (t < 49) {                       // kernel 0: 7x7 dil 64
            int dy = t / 7 - 3, dx = t % 7 - 3;
            float py = dy * 64.0f / fs[0], px = dx * 64.0f / fs[1];
            d[(t / 7) * 8 + t % 7] =
                log2f(w0[s * 49 + t]) + NH * (py * py + px * px);
        } else if (t >= 64 && t < 113) {    // kernel 1: 7x7 dil 16
            int u = t - 64;
            int dy = u / 7 - 3, dx = u % 7 - 3;
            float py = dy * 16.0f / fs[5], px = dx * 16.0f / fs[6];
            d[56 + (u / 7) * 8 + u % 7] =
                log2f(w1[s * 49 + u]) + NH * (py * py + px * px);
        } else if (t >= 128 && t < 209) {   // kernel 2: 9x9 dil 1
            int u = t - 128;
            int dy = u / 9 - 4, dx = u % 9 - 4;
            float py = dy / fs[10], px = dx / fs[11];
            d[112 + (u / 9) * 12 + u % 9] =
                log2f(w2[s * 81 + u]) + NH * (py * py + px * px);
        } else if (t == 224) {
            float r1 = fs[2] / fs[7], r2 = fs[2] / fs[12];
            d[220] = NH;
            d[221] = NH * r1 * r1;
            d[222] = NH * r2 * r2;
            d[223] = c0[s * 4 + 0];  d[224] = c0[s * 4 + 1];
            d[225] = c0[s * 4 + 2];  d[226] = c0[s * 4 + 3];
            d[227] = c1[s * 4 + 0];  d[228] = c1[s * 4 + 1];
            d[229] = c1[s * 4 + 2];  d[230] = c1[s * 4 + 3];
            d[231] = pwArr[s * 3 + 0];
            d[232] = pwArr[s * 3 + 1];
            d[233] = pwArr[s * 3 + 2];
            d[234] = uwArr[s] * 5.0f;
        }
    }

    // ---- plane init: cells 2*idx and 2*idx+1 (same padded row: PSTR even) ----
    int idx = blockIdx.x * 256 + threadIdx.x;
    if (idx >= PCELLS / 2) return;
    int c0i = 2 * idx;
    int y = c0i / PSTR, x0 = c0i - y * PSTR;
    int iy = y - PAD;

    uint4 vB = make_uint4(0x7BFF7BFFu, 0x00007BFFu, 0x7BFF7BFFu, 0x00007BFFu);
    uint4 vA = vB;

    if (iy >= 0 && iy < HH) {
#pragma unroll
        for (int k = 0; k < 2; ++k) {
            int ix = x0 + k - PAD;
            if (ix >= 0 && ix < WW) {
                int p = iy * WW + ix;
                _Float16 rh = (_Float16)(xrgb[p] * (1.0f / fs[2]));
                _Float16 gh = (_Float16)(xrgb[HWSZ + p] * (1.0f / fs[3]));
                _Float16 bh = (_Float16)(xrgb[2 * HWSZ + p] * (1.0f / fs[4]));
                float l0 = unary[p], l1 = unary[HWSZ + p];
                float q = 1.0f / (1.0f + __expf(5.0f * (l1 - l0)));
                unsigned rg = h2u(h2{rh, gh});
                unsigned b0 = h2u(h2{bh, (_Float16)0});
                unsigned bq = h2u(h2{bh, (_Float16)q});
                if (k == 0) { vB.x = rg; vB.y = b0; vA.x = rg; vA.y = bq; }
                else        { vB.z = rg; vB.w = b0; vA.z = rg; vA.w = bq; }
            }
        }
    }
    PA4[idx] = vA;
    PB4[idx] = vB;
}

// ---------------------------------------------------------------------------
// One tap on an 8-B cell (R10-verified arithmetic, 8 issue ops).
// ---------------------------------------------------------------------------
__device__ __forceinline__ void tap8(uint2 aq, h2 rgp, h2 bqp, float nk,
                                     float tpv, float& A, float& B)
{
    h2 drg = bch2(aq.x) - rgp;
    h2 dbq = bch2(aq.y) - bqp;
    float s1 = fdot2f(drg, drg, 0.0f);
    float db = (float)dbq.x;
    float ssq = fmaf(db, db, s1);
    float e = EXP2(fmaf(ssq, nk, tpv));
    A = fmaf(e, (float)bch2(aq.y).y, A);   // q = hi half -> v_fma_mix
    B += e;
}

// k0 chunk helpers: static indices only (full unroll).
template <int T0, int N>
__device__ __forceinline__ void loadK0(uint2 (&buf)[N], const uint2* __restrict__ Pc)
{
#pragma unroll
    for (int t = 0; t < N; ++t) {
        const int tt = T0 + t;
        buf[t] = Pc[(tt / 7 - 3) * 64 * PSTR + (tt % 7 - 3) * 64];
    }
}
template <int T0, int N>
__device__ __forceinline__ void compK0(const uint2 (&buf)[N],
                                       const float* __restrict__ tp0,
                                       h2 rgp, h2 bqp, float nk,
                                       float& A, float& B)
{
#pragma unroll
    for (int t = 0; t < N; ++t) {
        const int tt = T0 + t;
        tap8(buf[t], rgp, bqp, nk, tp0[(tt / 7) * 8 + tt % 7], A, B);
    }
}
// k1 chunk from LDS.
template <int T0, int N>
__device__ __forceinline__ void compK1(const uint2* __restrict__ T1b,
                                       const float* __restrict__ tp1,
                                       h2 rgp, h2 bqp, float nk,
                                       float& A, float& B)
{
#pragma unroll
    for (int t = 0; t < N; ++t) {
        const int tt = T0 + t;
        tap8(T1b[(tt / 7) * 448 + (tt % 7) * 16], rgp, bqp, nk,
             tp1[(tt / 7) * 8 + tt % 7], A, B);
    }
}
// k2 chunk from LDS.
template <int T0, int N>
__device__ __forceinline__ void compK2(const uint2* __restrict__ T2b,
                                       const float* __restrict__ tp2,
                                       h2 rgp, h2 bqp, float nk,
                                       float& A, float& B)
{
#pragma unroll
    for (int t = 0; t < N; ++t) {
        const int tt = T0 + t;
        tap8(T2b[(tt / 9) * 136 + tt % 9], rgp, bqp, nk,
             tp2[(tt / 9) * 12 + tt % 9], A, B);
    }
}

// ---------------------------------------------------------------------------
// Fused step (R10/R16-proven, byte-identical to R16). Block = 128x2.
// k1/k2 from LDS tiles, k0 4-chunk reg-prefetched (chunk A pre-barrier),
// constants via uniform s_load. Non-last steps write only q' (1 dword).
// ---------------------------------------------------------------------------
template <bool LAST>
__global__ __launch_bounds__(256, 4) void crf_step(
    const uint2* __restrict__ srcP, unsigned* __restrict__ dstPw,
    const float* __restrict__ unary, const float* __restrict__ tpAll,
    int step, float* __restrict__ out)
{
    __shared__ uint2 T1[14 * 224];   // k1 tile: 25088 B
    __shared__ uint2 T2[10 * 136];   // k2 tile: 10880 B

    int tid = threadIdx.y * 128 + threadIdx.x;
    int x0 = blockIdx.x * 128, y0 = blockIdx.y * 2;

    // ---- stage k1 tile (waves 0-1) and k2 tile (waves 2-3) concurrently ----
#pragma unroll
    for (int r = 0; r < 14; ++r) {
        if (tid < 112) {
            int gy = y0 + 16 * (r >> 1) + (r & 1) - 48;
            const uint4* srow = (const uint4*)
                (srcP + (gy + PAD) * PSTR + (x0 - 48 + PAD));
            ((uint4*)T1)[r * 112 + tid] = srow[tid];
        }
    }
#pragma unroll
    for (int r = 0; r < 10; ++r) {
        int t2 = tid - 128;
        if (t2 >= 0 && t2 < 68) {
            int gy = y0 - 4 + r;
            const uint4* srow = (const uint4*)
                (srcP + (gy + PAD) * PSTR + (x0 - 4 + PAD));
            ((uint4*)T2)[r * 68 + t2] = srow[t2];
        }
    }

    int x = x0 + threadIdx.x;
    int y = y0 + threadIdx.y;
    int p = y * WW + x;
    int ccell = (y + PAD) * PSTR + x + PAD;

    // uniform tables -> s_load (issue early, independent of staging)
    const float* tp0 = tpAll + step * TPSTRIDE;
    const float* tp1 = tp0 + 56;
    const float* tp2 = tp0 + 112;
    const float* sc  = tp0 + 220;
    float nk0 = sc[0], nk1 = sc[1], nk2 = sc[2];

    const uint2* Pc = srcP + ccell;
    uint2 cw = make_uint2(0u, 0u);
    float un0 = 0.f, un1 = 0.f;
    uint2 bA[13];
    bool act = (x < WW);
    if (act) {
        cw = *Pc;
        un0 = unary[p]; un1 = unary[HWSZ + p];
        loadK0<0, 13>(bA, Pc);       // chunk A in flight across the barrier
    }
    __syncthreads();
    if (!act) return;

    h2 rgp = bch2(cw.x);
    h2 bqp = bch2(cw.y);

    const uint2* T1b = T1 + threadIdx.y * 224 + threadIdx.x;
    const uint2* T2b = T2 + threadIdx.y * 136 + threadIdx.x;

    float A0 = 0.f, B0 = 0.f, A1 = 0.f, B1 = 0.f, A2 = 0.f, B2 = 0.f;

    // ---- k0 register pipeline interleaved with k1/k2 LDS compute ----
    uint2 bB[12], bC[12], bD[12];
    loadK0<13, 12>(bB, Pc);
    compK2<0, 20>(T2b, tp2, rgp, bqp, nk2, A2, B2);
    compK0<0, 13>(bA, tp0, rgp, bqp, nk0, A0, B0);
    loadK0<25, 12>(bC, Pc);
    compK2<20, 20>(T2b, tp2, rgp, bqp, nk2, A2, B2);
    compK0<13, 12>(bB, tp0, rgp, bqp, nk0, A0, B0);
    loadK0<37, 12>(bD, Pc);
    compK1<0, 25>(T1b, tp1, rgp, bqp, nk1, A1, B1);
    compK0<25, 12>(bC, tp0, rgp, bqp, nk0, A0, B0);
    compK2<40, 20>(T2b, tp2, rgp, bqp, nk2, A2, B2);
    compK0<37, 12>(bD, tp0, rgp, bqp, nk0, A0, B0);
    compK1<25, 24>(T1b, tp1, rgp, bqp, nk1, A1, B1);
    compK2<60, 21>(T2b, tp2, rgp, bqp, nk2, A2, B2);

    float m00 = A0, m01 = B0 - A0;
    float m10 = A1, m11 = B1 - A1;
    float m20 = A2, m21 = B2 - A2;

    float r00 = sc[3] * m00 + sc[4] * m01;
    float r01 = sc[5] * m00 + sc[6] * m01;
    float r10 = sc[7] * m10 + sc[8] * m11;
    float r11 = sc[9] * m10 + sc[10] * m11;

    float pw0 = sc[11], pw1 = sc[12], pw2 = sc[13], uw5 = sc[14];
    float o0 = uw5 * un0 + pw0 * r00 + pw1 * r10 + pw2 * m20;
    float o1 = uw5 * un1 + pw0 * r01 + pw1 * r11 + pw2 * m21;

    if (LAST) {
        out[p] = o0;
        out[HWSZ + p] = o1;
    } else {
        float qn = 1.0f / (1.0f + __expf(o1 - o0));
        unsigned nb = (h2u(bqp) & 0xFFFFu) |
                      ((unsigned)hbits((_Float16)qn) << 16);
        dstPw[2 * ccell + 1] = nb;
    }
}

// ---------------------------------------------------------------------------
extern "C" void kernel_launch(void* const* d_in, const int* in_sizes, int n_in,
                              void* d_out, int out_size, void* d_ws, size_t ws_size,
                              hipStream_t stream)
{
    const float* unary = (const float*)d_in[0];
    const float* xrgb  = (const float*)d_in[1];
    const float* fs    = (const float*)d_in[2];
    // d_in[3] = potts_w (dead in reference forward)
    const float* uw    = (const float*)d_in[4];
    const float* pw    = (const float*)d_in[5];
    const float* w0    = (const float*)d_in[6];
    const float* w1    = (const float*)d_in[7];
    const float* w2    = (const float*)d_in[8];
    const float* c0    = (const float*)d_in[9];
    const float* c1    = (const float*)d_in[10];
    float* out = (float*)d_out;

    uint2* PA = (uint2*)d_ws;                               // 8.57 MB
    uint2* PB = (uint2*)((char*)d_ws + (size_t)PCELLS * 8); // 8.57 MB
    float* tpAll = (float*)((char*)d_ws + (size_t)PCELLS * 16);

    int initBlocks = (PCELLS / 2 + 255) / 256;   // 2093 >= 5
    init_all<<<initBlocks, 256, 0, stream>>>(xrgb, unary, fs, uw, pw,
                                             w0, w1, w2, c0, c1,
                                             (uint4*)PA, (uint4*)PB, tpAll);

    dim3 gs((WW + 127) / 128, HH / 2), bs(128, 2);
    for (int s = 0; s < 5; ++s) {
        const uint2* src = (s & 1) ? PB : PA;
        unsigned* dst = (unsigned*)((s & 1) ? PA : PB);
        if (s < 4)
            crf_step<false><<<gs, bs, 0, stream>>>(src, dst, unary, tpAll,
                                                   s, out);
        else
            crf_step<true><<<gs, bs, 0, stream>>>(src, dst, unary, tpAll,
                                                  s, out);
    }
}